// Round 4
// baseline (378.581 us; speedup 1.0000x reference)
//
#include <hip/hip_runtime.h>
#include <hip/hip_bf16.h>

#define HD 192
#define H2 384
#define NOUT 5

typedef __attribute__((ext_vector_type(4))) float f32x4;
typedef __attribute__((ext_vector_type(8))) short bf16x8;
typedef long long ll;

__device__ __forceinline__ ushort f2bf(float f) {
    union { float f; unsigned u; } v; v.f = f;
    unsigned r = v.u + 0x7FFF + ((v.u >> 16) & 1);   // RNE
    return (ushort)(r >> 16);
}
__device__ __forceinline__ float bf2f(ushort s) {
    union { unsigned u; float f; } v; v.u = ((unsigned)s) << 16;
    return v.f;
}

// ---- Vt f32 -> bf16, XCD-affine: WG blk converts rows [blk*64, blk*64+64) --
// Same blk->rows mapping as gemm_level_kernel, so the XCD that writes a Vtb
// slice is the XCD that reads it in every level (L2-local, no remote-dirty).
__global__ __launch_bounds__(256) void convert_kernel(const float* __restrict__ src,
                                                      ushort* __restrict__ dst) {
    const ll base = (ll)blockIdx.x * (64 * H2);       // elements
    for (int i = threadIdx.x; i < 3072; i += 256) {   // 3072 * 8 = 24576 elems
        ll e = base + (ll)i * 8;
        float4 a = *(const float4*)(src + e);
        float4 b = *(const float4*)(src + e + 4);
        ushort o[8] = { f2bf(a.x), f2bf(a.y), f2bf(a.z), f2bf(a.w),
                        f2bf(b.x), f2bf(b.y), f2bf(b.z), f2bf(b.w) };
        *(uint4*)(dst + e) = *(uint4*)o;
    }
}

// ---- leaves: gather embed rows; zero xbuf and C5 pad -----------------------
__global__ void leaf_kernel(const float* __restrict__ embed, const int* __restrict__ leaf_ids,
                            float* __restrict__ nodes, ushort* __restrict__ C1,
                            ushort* __restrict__ C5, float* __restrict__ xbuf) {
    int r = blockIdx.x;       // 0..255
    int t = threadIdx.x;      // 0..191
    int id = leaf_ids[r];
    float v = embed[(ll)id * HD + t];
    nodes[r * HD + t] = v;
    C1[r * HD + t] = f2bf(v);
    int idx = r * HD + t;                    // 0..49151
    if (idx < HD * 128) xbuf[idx] = 0.f;     // zero 192*128 accumulator
    if (r == 0) {                            // zero pad rows 8..15 of C5 [16][384]
        for (int i = t; i < 8 * H2; i += HD) C5[8 * H2 + i] = 0;
    }
}

// ---- per-level fused GEMM + (xVx + Wx) contraction -------------------------
// 1152 WGs; WG blk: h = blk/6, x-block xb0 = (blk%6)*64, A rows R0 = blk*64.
// Each wave holds its 16 A rows (12 bf16x8 frags) in registers; B (= C_l,
// <=98 KB, L2-resident) is read directly from global. Epilogue computes
// sum_x (acc_x + W[x,h]) * c[n,x] over the WG's 64 x's -> atomicAdd xbuf[h][n].
template<int NT>
__global__ __launch_bounds__(256, 4) void gemm_level_kernel(const ushort* __restrict__ Vtb,
        const ushort* __restrict__ Cl, const float* __restrict__ W, float* __restrict__ xbuf) {
    __shared__ float wl[64];
    __shared__ float red[128];               // [4 waves][32]
    const int tid = threadIdx.x, lane = tid & 63, wave = tid >> 6;
    const int blk = blockIdx.x;
    const int h = blk / 6, xb0 = (blk % 6) * 64;
    const int lr = lane & 15, hi = lane >> 4, lk = hi * 8, dr = hi * 4;

    if (tid < 64) wl[tid] = W[(xb0 + tid) * HD + h];

    // A fragments: 16 rows per wave, all K=384, in registers
    bf16x8 areg[12];
    const ushort* arow = Vtb + ((ll)blk * 64 + wave * 16 + lr) * H2;
#pragma unroll
    for (int kk = 0; kk < 12; kk++) areg[kk] = *(const bf16x8*)&arow[kk * 32 + lk];
    __syncthreads();

    constexpr int CHUNK = (NT >= 2) ? 2 : 1;
#pragma unroll
    for (int nc = 0; nc < NT / CHUNK; nc++) {
        f32x4 acc[CHUNK];
#pragma unroll
        for (int ci = 0; ci < CHUNK; ci++) acc[ci] = (f32x4){0.f, 0.f, 0.f, 0.f};
#pragma unroll
        for (int kk = 0; kk < 12; kk++) {
#pragma unroll
            for (int ci = 0; ci < CHUNK; ci++) {
                bf16x8 b = *(const bf16x8*)&Cl[((nc * CHUNK + ci) * 16 + lr) * H2 + kk * 32 + lk];
                acc[ci] = __builtin_amdgcn_mfma_f32_16x16x32_bf16(areg[kk], b, acc[ci], 0, 0, 0);
            }
        }
        // epilogue: rows loc..loc+3 (m89 C/D layout), add W col, multiply c[n,x]
        float part[CHUNK];
#pragma unroll
        for (int ci = 0; ci < CHUNK; ci++) {
            int n = (nc * CHUNK + ci) * 16 + lr;
            int loc = wave * 16 + dr;
            ushort4 cv = *(const ushort4*)&Cl[n * H2 + xb0 + loc];
            float4  wv = *(const float4*)&wl[loc];
            float p = (acc[ci][0] + wv.x) * bf2f(cv.x) + (acc[ci][1] + wv.y) * bf2f(cv.y)
                    + (acc[ci][2] + wv.z) * bf2f(cv.z) + (acc[ci][3] + wv.w) * bf2f(cv.w);
            p += __shfl_xor(p, 16);
            p += __shfl_xor(p, 32);
            part[ci] = p;
        }
        __syncthreads();                     // guard red[] reuse across nc
        if (lane < 16) {
#pragma unroll
            for (int ci = 0; ci < CHUNK; ci++) red[wave * 32 + ci * 16 + lane] = part[ci];
        }
        __syncthreads();
        if (tid < CHUNK * 16) {
            float s = red[tid] + red[32 + tid] + red[64 + tid] + red[96 + tid];
            atomicAdd(&xbuf[h * 128 + nc * CHUNK * 16 + tid], s);
        }
    }
}

// ---- per-level tanh: pre = xbuf + b; write nodes f32 + next C bf16; zero xbuf
__global__ void tanh_kernel(float* __restrict__ xbuf, const float* __restrict__ bvec,
                            float* __restrict__ nodes_base, ushort* __restrict__ Cnext, int Nl) {
    int hh = blockIdx.x, tid = threadIdx.x;  // 192 x 128
    float v = xbuf[hh * 128 + tid];
    xbuf[hh * 128 + tid] = 0.f;              // ready for next level's atomics
    if (tid < Nl) {
        float t = tanhf(v + bvec[hh]);
        nodes_base[tid * HD + hh] = t;
        if (Cnext) Cnext[(tid >> 1) * H2 + (tid & 1) * HD + hh] = f2bf(t);
    }
}

// ---- logits + log_softmax ---------------------------------------------------
__global__ void logits_kernel(const float* __restrict__ nodes, const float* __restrict__ Ww,
                              const float* __restrict__ Wb, float* __restrict__ out) {
    int r = blockIdx.x, t = threadIdx.x;
    __shared__ float lg[NOUT];
    if (t < NOUT) {
        float s = Wb[t];
        const float* a = nodes + r * HD;
        const float* w = Ww + t * HD;
#pragma unroll 8
        for (int k = 0; k < HD; k++) s += a[k] * w[k];
        lg[t] = s;
    }
    __syncthreads();
    if (t < NOUT) {
        float m = lg[0];
        for (int i = 1; i < NOUT; i++) m = fmaxf(m, lg[i]);
        float sum = 0.f;
        for (int i = 0; i < NOUT; i++) sum += expf(lg[i] - m);
        out[r * NOUT + t] = lg[t] - m - logf(sum);
    }
}

extern "C" void kernel_launch(void* const* d_in, const int* in_sizes, int n_in,
                              void* d_out, int out_size, void* d_ws, size_t ws_size,
                              hipStream_t stream) {
    const float* embed    = (const float*)d_in[0];
    const float* Vt       = (const float*)d_in[1];
    const float* W        = (const float*)d_in[2];
    const float* bvec     = (const float*)d_in[3];
    const float* Ww       = (const float*)d_in[4];
    const float* Wb       = (const float*)d_in[5];
    const int*   leaf_ids = (const int*)d_in[6];
    float* out = (float*)d_out;

    char* ws = (char*)d_ws;
    size_t off = 0;
    ushort* Vtb  = (ushort*)(ws + off); off += (size_t)73728 * H2 * 2;  // 56.6 MB
    float*  nodes= (float*) (ws + off); off += (size_t)504 * HD * 4;
    ushort* C1   = (ushort*)(ws + off); off += (size_t)128 * H2 * 2;
    ushort* C2   = (ushort*)(ws + off); off += (size_t)64  * H2 * 2;
    ushort* C3   = (ushort*)(ws + off); off += (size_t)32  * H2 * 2;
    ushort* C4   = (ushort*)(ws + off); off += (size_t)16  * H2 * 2;
    ushort* C5   = (ushort*)(ws + off); off += (size_t)16  * H2 * 2;
    float*  X    = (float*) (ws + off); off += (size_t)HD * 128 * 4;    // xVx+Wx accumulator

    convert_kernel<<<1152, 256, 0, stream>>>(Vt, Vtb);
    leaf_kernel<<<256, HD, 0, stream>>>(embed, leaf_ids, nodes, C1, C5, X);

    // level 1: N=128
    gemm_level_kernel<8><<<1152, 256, 0, stream>>>(Vtb, C1, W, X);
    tanh_kernel<<<HD, 128, 0, stream>>>(X, bvec, nodes + 256 * HD, C2, 128);
    // level 2: N=64
    gemm_level_kernel<4><<<1152, 256, 0, stream>>>(Vtb, C2, W, X);
    tanh_kernel<<<HD, 128, 0, stream>>>(X, bvec, nodes + 384 * HD, C3, 64);
    // level 3: N=32
    gemm_level_kernel<2><<<1152, 256, 0, stream>>>(Vtb, C3, W, X);
    tanh_kernel<<<HD, 128, 0, stream>>>(X, bvec, nodes + 448 * HD, C4, 32);
    // level 4: N=16
    gemm_level_kernel<1><<<1152, 256, 0, stream>>>(Vtb, C4, W, X);
    tanh_kernel<<<HD, 128, 0, stream>>>(X, bvec, nodes + 480 * HD, C5, 16);
    // level 5: N=8 (C5 rows 8..15 zeroed by leaf -> cols 8..15 contribute 0)
    gemm_level_kernel<1><<<1152, 256, 0, stream>>>(Vtb, C5, W, X);
    tanh_kernel<<<HD, 128, 0, stream>>>(X, bvec, nodes + 496 * HD, (ushort*)nullptr, 8);

    logits_kernel<<<504, 64, 0, stream>>>(nodes, Ww, Wb, out);
}